// Round 6
// baseline (392.855 us; speedup 1.0000x reference)
//
#include <hip/hip_runtime.h>

// EEGGraphClf graph-loss, fused single pass over A. B=64, N=1024, D=16.
//
// loss[b] = 0.2 * [ sum_n deg_n*||f_n||^2 - sum_j f_j . w_j ] / N^2
//         - 0.1 * sum_n log(deg_n + 1e-12) / N
//         + 0.1 * sum_{n,j} A[n,j]^2 / N^2
//   with w_j = sum_n A[n,j] * f_n   (register accumulators, dotted once at end)
//
// 16 blocks/batch, block = 64 rows x 1024 cols, 512 threads, 2 cols/thread.
//
// R5 post-mortem: perf tracks OCCUPANCY monotonically (R3 8w/SIMD=86us,
// R4 ~6w=91, R5 ~3w=112); depth/width/f-path all neutral. Latency-bound
// stream: resident waves are the parallelism multiplier. R3's remaining
// per-row stall: 2 dependent ds_swizzle (shfl) + lgkmcnt waits.
// R6 = R3 exactly, with the deg 4-lane reduce switched from shfl (DS pipe,
// ~40cy each, lgkm-serialized) to DPP quad_perm adds (pure VALU, ~4cy,
// no lgkm). Loop lgkm domain = f s_loads (1-row prefetch, hidden under
// ~600cy contended VALU) + 1 fire-and-forget ds_write/row.
// launch_bounds(512,8) FORCES VGPR<=64 -> 4 blocks/CU, 32 waves/CU.
// Live set ~54 regs -> no spill (check: WRITE_SIZE must stay ~0.1MB).

#define NN      1024
#define DD      16
#define ROWS    64
#define TPB     512
#define GRPS    128        // 512 threads / 4 = 128 deg groups per row
#define SMOOTHR 0.2f
#define DEGRR   0.1f
#define SPARSR  0.1f
#define EPSV    1e-12f

typedef float vf4 __attribute__((ext_vector_type(4)));
typedef float vf2 __attribute__((ext_vector_type(2)));

__global__ __launch_bounds__(TPB, 8)
void graph_loss_kernel(const float* __restrict__ A,
                       const float* __restrict__ F,
                       float* __restrict__ out) {
    __shared__ float degq[ROWS][GRPS + 1];   // 33 KB, stride 129
    __shared__ float wred[8][2];

    const int tid = threadIdx.x;
    const int bid = blockIdx.x;
    const int b   = bid >> 4;
    const int n0  = (bid & 15) * ROWS;

    const float* __restrict__ Fb = F + (size_t)b * NN * DD;
    const float* __restrict__ Ab = A + ((size_t)b * NN + n0) * NN;

    // ---- per-thread state: w0/w1 = 32 VGPR accumulators ----
    float w0[16], w1[16];
    #pragma unroll
    for (int k = 0; k < 16; ++k) { w0[k] = 0.f; w1[k] = 0.f; }

    float sq = 0.f;
    const float* __restrict__ arow = Ab + 2 * tid;
    const int  g       = tid >> 2;           // 4 threads = 8 cols per group
    const bool deglane = (tid & 3) == 0;

    #define LOADR(r) (*(const vf2*)(arow + (size_t)(r) * NN))
    // wave-uniform row features -> scalar s_load into SGPRs (no vmcnt, no VGPR)
    #define LDF(dst, rr)                                                     \
        do {                                                                 \
            const vf4* __restrict__ Fr =                                     \
                (const vf4*)(Fb + (size_t)(n0 + (rr)) * DD);                 \
            dst##0 = Fr[0]; dst##1 = Fr[1]; dst##2 = Fr[2]; dst##3 = Fr[3];  \
        } while (0)
    // quad (4-lane) sum via DPP: pure VALU, no DS ops, no lgkm waits.
    // quad_perm[1,0,3,2]=0xB1, quad_perm[2,3,0,1]=0x4E.
    #define QUADRED(s_)                                                      \
        do {                                                                 \
            s_ += __builtin_bit_cast(float, __builtin_amdgcn_update_dpp(     \
                0, __builtin_bit_cast(int, s_), 0xB1, 0xF, 0xF, true));      \
            s_ += __builtin_bit_cast(float, __builtin_amdgcn_update_dpp(     \
                0, __builtin_bit_cast(int, s_), 0x4E, 0xF, 0xF, true));      \
        } while (0)
    #define COMPUTE(av, f0v, f1v, f2v, f3v, rr)                              \
        do {                                                                 \
            float s_ = av.x + av.y;                                          \
            QUADRED(s_);                                                     \
            if (deglane) degq[(rr)][g] = s_;                                 \
            sq += av.x * av.x + av.y * av.y;                                 \
            w0[0]  += av.x * f0v.x;  w1[0]  += av.y * f0v.x;                 \
            w0[1]  += av.x * f0v.y;  w1[1]  += av.y * f0v.y;                 \
            w0[2]  += av.x * f0v.z;  w1[2]  += av.y * f0v.z;                 \
            w0[3]  += av.x * f0v.w;  w1[3]  += av.y * f0v.w;                 \
            w0[4]  += av.x * f1v.x;  w1[4]  += av.y * f1v.x;                 \
            w0[5]  += av.x * f1v.y;  w1[5]  += av.y * f1v.y;                 \
            w0[6]  += av.x * f1v.z;  w1[6]  += av.y * f1v.z;                 \
            w0[7]  += av.x * f1v.w;  w1[7]  += av.y * f1v.w;                 \
            w0[8]  += av.x * f2v.x;  w1[8]  += av.y * f2v.x;                 \
            w0[9]  += av.x * f2v.y;  w1[9]  += av.y * f2v.y;                 \
            w0[10] += av.x * f2v.z;  w1[10] += av.y * f2v.z;                 \
            w0[11] += av.x * f2v.w;  w1[11] += av.y * f2v.w;                 \
            w0[12] += av.x * f3v.x;  w1[12] += av.y * f3v.x;                 \
            w0[13] += av.x * f3v.y;  w1[13] += av.y * f3v.y;                 \
            w0[14] += av.x * f3v.z;  w1[14] += av.y * f3v.z;                 \
            w0[15] += av.x * f3v.w;  w1[15] += av.y * f3v.w;                 \
        } while (0)

    // ---- prologue: 4-row A prefetch, f double-buffer (SGPRs) ----
    vf2 a0 = LOADR(0);
    vf2 a1 = LOADR(1);
    vf2 a2 = LOADR(2);
    vf2 a3 = LOADR(3);
    vf4 fA0, fA1, fA2, fA3, fB0, fB1, fB2, fB3;
    LDF(fA, 0);

    // ---- main loop: 4 rows/iter, zero barriers, no DS reads ----
    #pragma unroll 1
    for (int r = 0; r < ROWS - 4; r += 4) {
        LDF(fB, r + 1);
        COMPUTE(a0, fA0, fA1, fA2, fA3, r);
        a0 = LOADR(r + 4);
        LDF(fA, r + 2);
        COMPUTE(a1, fB0, fB1, fB2, fB3, r + 1);
        a1 = LOADR(r + 5);
        LDF(fB, r + 3);
        COMPUTE(a2, fA0, fA1, fA2, fA3, r + 2);
        a2 = LOADR(r + 6);
        LDF(fA, r + 4);
        COMPUTE(a3, fB0, fB1, fB2, fB3, r + 3);
        a3 = LOADR(r + 7);
    }
    // tail: rows ROWS-4..ROWS-1 in a0..a3, fA holds row ROWS-4
    LDF(fB, ROWS - 3);
    COMPUTE(a0, fA0, fA1, fA2, fA3, ROWS - 4);
    LDF(fA, ROWS - 2);
    COMPUTE(a1, fB0, fB1, fB2, fB3, ROWS - 3);
    LDF(fB, ROWS - 1);
    COMPUTE(a2, fA0, fA1, fA2, fA3, ROWS - 2);
    COMPUTE(a3, fB0, fB1, fB2, fB3, ROWS - 1);

    #undef LOADR
    #undef LDF
    #undef QUADRED
    #undef COMPUTE

    // ---- finalize degrees: deg_n, log(deg_n), deg_n*||f_n||^2 (wave 0) ----
    __syncthreads();
    float lg = 0.f, dfn = 0.f;
    if (tid < ROWS) {
        float s0 = 0.f, s1 = 0.f, s2 = 0.f, s3 = 0.f;   // 4-way ILP split
        #pragma unroll
        for (int i = 0; i < GRPS / 4; ++i) {
            s0 += degq[tid][4 * i + 0];
            s1 += degq[tid][4 * i + 1];
            s2 += degq[tid][4 * i + 2];
            s3 += degq[tid][4 * i + 3];
        }
        const float s = (s0 + s1) + (s2 + s3);
        lg = logf(s + EPSV);
        const float* p = Fb + (size_t)(n0 + tid) * DD;
        float t = 0.f;
        #pragma unroll
        for (int q = 0; q < 4; ++q) {
            const vf4 f = *(const vf4*)(p + 4 * q);
            t += f.x * f.x + f.y * f.y + f.z * f.z + f.w * f.w;
        }
        dfn = s * t;
    }

    // ---- dot own columns' features against w (8 vf4 global loads, once) ----
    float dot = 0.f;
    {
        const vf4* __restrict__ P = (const vf4*)(Fb + (size_t)(2 * tid) * DD);
        #pragma unroll
        for (int q = 0; q < 4; ++q) {
            const vf4 f = P[q];
            dot += f.x * w0[4*q] + f.y * w0[4*q+1] + f.z * w0[4*q+2] + f.w * w0[4*q+3];
        }
        #pragma unroll
        for (int q = 0; q < 4; ++q) {
            const vf4 f = P[4 + q];
            dot += f.x * w1[4*q] + f.y * w1[4*q+1] + f.z * w1[4*q+2] + f.w * w1[4*q+3];
        }
    }

    // ---- block reduction: dot/sq across 8 waves; lg/dfn live in wave 0 ----
    #pragma unroll
    for (int m = 1; m < 64; m <<= 1) {
        dot += __shfl_xor(dot, m);
        sq  += __shfl_xor(sq, m);
        lg  += __shfl_xor(lg, m);
        dfn += __shfl_xor(dfn, m);
    }
    const int wv = tid >> 6;
    if ((tid & 63) == 0) { wred[wv][0] = dot; wred[wv][1] = sq; }
    __syncthreads();
    if (tid == 0) {
        float Dt = 0.f, Q = 0.f;
        #pragma unroll
        for (int i = 0; i < 8; ++i) { Dt += wred[i][0]; Q += wred[i][1]; }
        const float denom = (float)NN * (float)NN;
        const float contrib = SMOOTHR * (dfn - Dt) / denom
                            - DEGRR * lg / (float)NN
                            + SPARSR * Q / denom;
        atomicAdd(out + b, contrib);
    }
}

extern "C" void kernel_launch(void* const* d_in, const int* in_sizes, int n_in,
                              void* d_out, int out_size, void* d_ws, size_t ws_size,
                              hipStream_t stream) {
    const float* A = (const float*)d_in[0];   // out_adj [B,N,N]
    const float* F = (const float*)d_in[1];   // features [B,N,D]
    float* out = (float*)d_out;               // [B]

    const int B = out_size;                   // 64
    (void)hipMemsetAsync(d_out, 0, (size_t)B * sizeof(float), stream);
    graph_loss_kernel<<<dim3(B * (NN / ROWS)), dim3(TPB), 0, stream>>>(A, F, out);
}